// Round 8
// baseline (239.868 us; speedup 1.0000x reference)
//
#include <hip/hip_runtime.h>
#include <stdint.h>

#define N_ANCH 12288
#define NCLS 64
#define TOTW 192              // 64-bit words over all sorted anchors
#define INL 6                 // inline (word,mask) slots per row record
#define CAPO 192              // overflow capacity per row (>= 192-INL, provably enough)

typedef unsigned long long u64;
typedef unsigned int u32;
typedef unsigned char u8;

// IoU > 0.5 predicate, replicating numpy op order/rounding exactly (no FMA contraction).
__device__ __forceinline__ bool iou_gt(float4 a, float fa, float4 b, float fb) {
    float xx1 = fmaxf(a.x, b.x);
    float yy1 = fmaxf(a.y, b.y);
    float xx2 = fminf(a.z, b.z);
    float yy2 = fminf(a.w, b.w);
    float dx = fmaxf(__fsub_rn(xx2, xx1), 0.0f);
    float dy = fmaxf(__fsub_rn(yy2, yy1), 0.0f);
    float inter = __fmul_rn(dx, dy);
    float denom = __fadd_rn(__fsub_rn(__fadd_rn(fa, fb), inter), 1e-9f);
    float iou = __fdiv_rn(inter, denom);
    return iou > 0.5f;
}

// ---------------- decode: boxes, score, sortable key, area (+ zero valid/kept + rec.wc) ----------------
__global__ void decode_kernel(const float4* __restrict__ loc, const float* __restrict__ cls,
                              float4* __restrict__ boxes, float* __restrict__ score,
                              u32* __restrict__ key, float* __restrict__ area,
                              u64* __restrict__ zbase, u64* __restrict__ rec8) {
    int i = blockIdx.x * 256 + threadIdx.x;
    if (i < 384) zbase[i] = 0ull;          // valid_w(192) + kept_w(192)
    if (i >= N_ANCH) return;
    rec8[(size_t)i * 8] = 0ull;            // rec header word (wc) for row i
    float4 l = loc[i];
    int y = i >> 7;        // FM_W = 128
    int x = i & 127;
    float cx = (x + 0.5f) * 8.0f;   // exact
    float cy = (y + 0.5f) * 8.0f;   // exact
    float px = __fadd_rn(__fmul_rn(l.x, 32.0f), cx);
    float py = __fadd_rn(__fmul_rn(l.y, 32.0f), cy);
    float pw = __fmul_rn(expf(l.z), 32.0f);
    float ph = __fmul_rn(expf(l.w), 32.0f);
    float hx = __fmul_rn(pw, 0.5f);
    float hy = __fmul_rn(ph, 0.5f);
    float x1 = __fsub_rn(px, hx), y1 = __fsub_rn(py, hy);
    float x2 = __fadd_rn(px, hx), y2 = __fadd_rn(py, hy);
    float4 b; b.x = x1; b.y = y1; b.z = x2; b.w = y2;
    boxes[i] = b;
    area[i] = __fmul_rn(__fsub_rn(x2, x1), __fsub_rn(y2, y1));

    const float4* cr = (const float4*)(cls + (size_t)i * NCLS);
    float mx = -INFINITY;
#pragma unroll
    for (int k = 0; k < 16; ++k) {
        float4 v = cr[k];
        mx = fmaxf(mx, fmaxf(fmaxf(v.x, v.y), fmaxf(v.z, v.w)));
    }
    float s;
    if (mx >= 0.0f) {
        float e = expf(-mx);
        s = __fdiv_rn(1.0f, __fadd_rn(1.0f, e));
    } else {
        float e = expf(mx);
        s = __fdiv_rn(e, __fadd_rn(1.0f, e));
    }
    score[i] = s;
    float se = (s > 0.5f) ? s : -INFINITY;   // score_eff
    u32 u = __float_as_uint(se);
    u = (u & 0x80000000u) ? ~u : (u | 0x80000000u);   // ascending-ordered uint
    key[i] = u;
}

// ---------------- rank sort: stable descending argsort via O(N^2) rank ----------------
__global__ void rank_kernel(const u32* __restrict__ key, const float4* __restrict__ boxes,
                            const float* __restrict__ area, const float* __restrict__ score,
                            int* __restrict__ rankp, float4* __restrict__ sboxes,
                            float* __restrict__ sarea, u64* __restrict__ valid_words) {
    int tid = threadIdx.x;
    int part = tid & 31;
    int row = blockIdx.x * 8 + (tid >> 5);
    u32 ki = key[row];
    const uint4* kp = (const uint4*)key;
    int r = 0;
#pragma unroll 8
    for (int q = 0; q < 96; ++q) {           // 96*32 = 3072 uint4 = 12288 keys
        uint4 v = kp[(q << 5) + part];
        int j0 = (q << 7) + (part << 2);
        r += (int)(v.x > ki) + (int)((v.x == ki) & (j0 + 0 < row));
        r += (int)(v.y > ki) + (int)((v.y == ki) & (j0 + 1 < row));
        r += (int)(v.z > ki) + (int)((v.z == ki) & (j0 + 2 < row));
        r += (int)(v.w > ki) + (int)((v.w == ki) & (j0 + 3 < row));
    }
    r += __shfl_xor(r, 1);
    r += __shfl_xor(r, 2);
    r += __shfl_xor(r, 4);
    r += __shfl_xor(r, 8);
    r += __shfl_xor(r, 16);
    if (part == 0) {
        rankp[row] = r;
        sboxes[r] = boxes[row];
        sarea[r] = area[row];
        if (score[row] > 0.5f) atomicOr(&valid_words[r >> 6], 1ull << (r & 63));
    }
}

// ---------------- pairs: sparse per-row (word, mask) lists into 64-B step-major records ----------------
// grid (48, 192): block = rows rg*64..+63 vs words 4wg..4wg+3. Each thread owns one (row, word).
__global__ void pairs_kernel(const float4* __restrict__ sboxes, const float* __restrict__ sarea,
                             u64* __restrict__ rec8, u8* __restrict__ ovw,
                             u64* __restrict__ ovm) {
    int wg = blockIdx.x, rg = blockIdx.y;
    if (4 * wg + 3 < rg) return;            // strictly lower-triangle tile
    __shared__ float4 rbox[64];  __shared__ float rarea[64];
    __shared__ float4 qbox[256]; __shared__ float qarea[256];
    int tid = threadIdx.x;
    if (tid < 64) { rbox[tid] = sboxes[rg * 64 + tid]; rarea[tid] = sarea[rg * 64 + tid]; }
    int qg = wg * 256 + tid;
    qbox[tid] = sboxes[qg];
    qarea[tid] = sarea[qg];
    __syncthreads();
    int row = tid >> 2;
    int wloc = tid & 3;
    int W = 4 * wg + wloc;
    if (W < rg) return;
    int p = rg * 64 + row;
    float4 bi = rbox[row];
    float ai = rarea[row];
    u64 mask = 0;
    int qb = wloc << 6;
#pragma unroll 8
    for (int j = 0; j < 64; ++j) {
        bool pred = iou_gt(bi, ai, qbox[qb + j], qarea[qb + j]);
        mask |= ((u64)pred) << j;
    }
    if (W == rg) mask &= (row == 63) ? 0ull : (~0ull << (row + 1));   // q > p within own word
    if (mask) {
        u32 slot = atomicAdd((u32*)&rec8[(size_t)p * 8], 1u);
        if (slot < INL) {
            ((u8*)&rec8[(size_t)p * 8 + 1])[slot] = (u8)W;   // w-bytes word, distinct byte per slot
            rec8[(size_t)p * 8 + 2 + slot] = mask;
        } else {
            u32 o = slot - INL;
            ovw[(size_t)p * CAPO + o] = (u8)W;
            ovm[(size_t)p * CAPO + o] = mask;
        }
    }
}

// ---------------- global serial greedy scan: ONE wave, 192 steps, 6-deep reg prefetch ----------------
__global__ void __launch_bounds__(64, 1)
scan_kernel(const u64* __restrict__ rec8, const u8* __restrict__ ovw,
            const u64* __restrict__ ovm, const u64* __restrict__ valid_w,
            u64* __restrict__ kept_w) {
    __shared__ u64 alive[TOTW];
    int lane = threadIdx.x;
#pragma unroll
    for (int k = 0; k < 3; ++k) alive[lane + 64 * k] = valid_w[lane + 64 * k];

    ulonglong4 A0, B0, A1, B1, A2, B2, A3, B3, A4, B4, A5, B5;

#define PREF(S, RA, RB) do { \
    const ulonglong4* rp_ = (const ulonglong4*)&rec8[(size_t)((S) * 64 + lane) * 8]; \
    RA = rp_[0]; RB = rp_[1]; \
} while (0)

    PREF(0, A0, B0); PREF(1, A1, B1); PREF(2, A2, B2);
    PREF(3, A3, B3); PREF(4, A4, B4); PREF(5, A5, B5);

#define STEPS(S, RA, RB) do { \
    int S_ = (S); \
    int r_ = S_ * 64 + lane; \
    u32 wc_ = (u32)RA.x; \
    u64 wb_ = RA.y; \
    u64 m0_ = RA.z, m1_ = RA.w, m2_ = RB.x, m3_ = RB.y, m4_ = RB.z, m5_ = RB.w; \
    u32 w0_ = (u32)(wb_ & 0xFF), w1_ = (u32)((wb_ >> 8) & 0xFF), w2_ = (u32)((wb_ >> 16) & 0xFF); \
    u32 w3_ = (u32)((wb_ >> 24) & 0xFF), w4_ = (u32)((wb_ >> 32) & 0xFF), w5_ = (u32)((wb_ >> 40) & 0xFF); \
    u64 own_s_ = 0; \
    own_s_ |= (wc_ > 0 && w0_ == (u32)S_) ? m0_ : 0ull; \
    own_s_ |= (wc_ > 1 && w1_ == (u32)S_) ? m1_ : 0ull; \
    own_s_ |= (wc_ > 2 && w2_ == (u32)S_) ? m2_ : 0ull; \
    own_s_ |= (wc_ > 3 && w3_ == (u32)S_) ? m3_ : 0ull; \
    own_s_ |= (wc_ > 4 && w4_ == (u32)S_) ? m4_ : 0ull; \
    own_s_ |= (wc_ > 5 && w5_ == (u32)S_) ? m5_ : 0ull; \
    if (wc_ > INL) { \
        u32 we_ = (wc_ <= 192u) ? wc_ : 192u; \
        for (u32 k_ = INL; k_ < we_; ++k_) { \
            u32 w_ = ovw[(size_t)r_ * CAPO + (k_ - INL)]; \
            if (w_ == (u32)S_) own_s_ |= ovm[(size_t)r_ * CAPO + (k_ - INL)]; \
        } \
    } \
    u64 suppmask_ = __ballot(own_s_ != 0ull); \
    u64 cur_ = alive[S_]; \
    u64 kept_ = 0; \
    while (true) { \
        u64 m_ = cur_ & suppmask_; \
        if (m_ == 0) { kept_ |= cur_; break; } \
        int t_ = __ffsll(m_) - 1; \
        u64 below_ = (t_ == 0) ? 0ull : (cur_ & ((1ull << t_) - 1ull)); \
        kept_ |= below_ | (1ull << t_); \
        u32 lo_ = __builtin_amdgcn_readlane((u32)own_s_, t_); \
        u32 hi_ = __builtin_amdgcn_readlane((u32)(own_s_ >> 32), t_); \
        u64 dw_ = ((u64)hi_ << 32) | (u64)lo_; \
        cur_ &= ~dw_; \
        cur_ &= (t_ == 63) ? 0ull : (~0ull << (t_ + 1)); \
    } \
    if (lane == 0) kept_w[S_] = kept_; \
    bool me_ = (kept_ >> lane) & 1ull; \
    if (me_) { \
        if (wc_ > 0 && w0_ > (u32)S_ && m0_) atomicAnd(&alive[w0_], ~m0_); \
        if (wc_ > 1 && w1_ > (u32)S_ && m1_) atomicAnd(&alive[w1_], ~m1_); \
        if (wc_ > 2 && w2_ > (u32)S_ && m2_) atomicAnd(&alive[w2_], ~m2_); \
        if (wc_ > 3 && w3_ > (u32)S_ && m3_) atomicAnd(&alive[w3_], ~m3_); \
        if (wc_ > 4 && w4_ > (u32)S_ && m4_) atomicAnd(&alive[w4_], ~m4_); \
        if (wc_ > 5 && w5_ > (u32)S_ && m5_) atomicAnd(&alive[w5_], ~m5_); \
        if (wc_ > INL) { \
            u32 we_ = (wc_ <= 192u) ? wc_ : 192u; \
            for (u32 k_ = INL; k_ < we_; ++k_) { \
                u32 w_ = ovw[(size_t)r_ * CAPO + (k_ - INL)]; \
                if (w_ > (u32)S_) { \
                    u64 b_ = ovm[(size_t)r_ * CAPO + (k_ - INL)]; \
                    if (b_) atomicAnd(&alive[w_], ~b_); \
                } \
            } \
        } \
    } \
    if (S_ + 6 < TOTW) PREF(S_ + 6, RA, RB); \
} while (0)

    for (int sb = 0; sb < TOTW; sb += 6) {
        STEPS(sb + 0, A0, B0);
        STEPS(sb + 1, A1, B1);
        STEPS(sb + 2, A2, B2);
        STEPS(sb + 3, A3, B3);
        STEPS(sb + 4, A4, B4);
        STEPS(sb + 5, A5, B5);
    }
}

// ---------------- output ----------------
__global__ void output_kernel(const float4* __restrict__ boxes, const float* __restrict__ score,
                              const int* __restrict__ rankp, const u64* __restrict__ kept_words,
                              float* __restrict__ out) {
    int i = blockIdx.x * 256 + threadIdx.x;
    if (i >= N_ANCH) return;
    int p = rankp[i];
    float m = ((kept_words[p >> 6] >> (p & 63)) & 1ull) ? 1.0f : 0.0f;
    float4 b = boxes[i];
    float s = score[i];
    out[(size_t)i * 5 + 0] = __fmul_rn(b.x, m);
    out[(size_t)i * 5 + 1] = __fmul_rn(b.y, m);
    out[(size_t)i * 5 + 2] = __fmul_rn(b.z, m);
    out[(size_t)i * 5 + 3] = __fmul_rn(b.w, m);
    out[(size_t)i * 5 + 4] = __fmul_rn(s, m);
}

extern "C" void kernel_launch(void* const* d_in, const int* in_sizes, int n_in,
                              void* d_out, int out_size, void* d_ws, size_t ws_size,
                              hipStream_t stream) {
    const float4* loc = (const float4*)d_in[0];
    const float* cls = (const float*)d_in[1];
    char* ws = (char*)d_ws;

    float4* boxes   = (float4*)(ws + 0);         // 196608
    float*  score   = (float*) (ws + 196608);    // 49152
    u32*    key     = (u32*)   (ws + 245760);    // 49152
    float*  area    = (float*) (ws + 294912);    // 49152
    int*    rankp   = (int*)   (ws + 344064);    // 49152
    float4* sboxes  = (float4*)(ws + 393216);    // 196608
    float*  sarea   = (float*) (ws + 589824);    // 49152
    u64*    valid_w = (u64*)   (ws + 638976);    // 1536
    u64*    kept_w  = (u64*)   (ws + 640512);    // 1536
    u64*    rec8    = (u64*)   (ws + 642048);    // 12288*64   = 786432
    u8*     ovw     = (u8*)    (ws + 1428480);   // 12288*192  = 2359296
    u64*    ovm     = (u64*)   (ws + 3787776);   // 12288*192*8 = 18874368 (end ~22.7 MB; ws ~256 MB)
    float*  out     = (float*)d_out;

    decode_kernel<<<48, 256, 0, stream>>>(loc, cls, boxes, score, key, area, valid_w, rec8);
    rank_kernel<<<1536, 256, 0, stream>>>(key, boxes, area, score, rankp, sboxes, sarea, valid_w);
    pairs_kernel<<<dim3(48, 192), 256, 0, stream>>>(sboxes, sarea, rec8, ovw, ovm);
    scan_kernel<<<1, 64, 0, stream>>>(rec8, ovw, ovm, valid_w, kept_w);
    output_kernel<<<48, 256, 0, stream>>>(boxes, score, rankp, kept_w, out);
}

// Round 9
// 148.682 us; speedup vs baseline: 1.6133x; 1.6133x over previous
//
#include <hip/hip_runtime.h>
#include <stdint.h>

#define N_ANCH 12288
#define NCLS 64
#define TOTW 192              // 64-bit words over all anchors (original index space)
#define CAPO 192              // overflow capacity per row (>= 192-6, provably enough)

typedef unsigned long long u64;
typedef unsigned int u32;
typedef unsigned char u8;

// IoU > 0.5 predicate, replicating numpy op order/rounding exactly (no FMA contraction).
// Symmetric in (a,b) up to exact float commutativity -> matches reference either way.
__device__ __forceinline__ bool iou_gt(float4 a, float fa, float4 b, float fb) {
    float xx1 = fmaxf(a.x, b.x);
    float yy1 = fmaxf(a.y, b.y);
    float xx2 = fminf(a.z, b.z);
    float yy2 = fminf(a.w, b.w);
    float dx = fmaxf(__fsub_rn(xx2, xx1), 0.0f);
    float dy = fmaxf(__fsub_rn(yy2, yy1), 0.0f);
    float inter = __fmul_rn(dx, dy);
    float denom = __fadd_rn(__fsub_rn(__fadd_rn(fa, fb), inter), 1e-9f);
    float iou = __fdiv_rn(inter, denom);
    return iou > 0.5f;
}

// ---------------- decode: boxes, score, order key, area; zero rec headers ----------------
__global__ void decode_kernel(const float4* __restrict__ loc, const float* __restrict__ cls,
                              float4* __restrict__ boxes, float* __restrict__ score,
                              u32* __restrict__ key, float* __restrict__ area,
                              u64* __restrict__ rec8) {
    int i = blockIdx.x * 256 + threadIdx.x;
    if (i >= N_ANCH) return;
    rec8[(size_t)i * 8] = 0ull;            // rec header (wc) for row i
    float4 l = loc[i];
    int y = i >> 7;        // FM_W = 128
    int x = i & 127;
    float cx = (x + 0.5f) * 8.0f;   // exact
    float cy = (y + 0.5f) * 8.0f;   // exact
    float px = __fadd_rn(__fmul_rn(l.x, 32.0f), cx);
    float py = __fadd_rn(__fmul_rn(l.y, 32.0f), cy);
    float pw = __fmul_rn(expf(l.z), 32.0f);
    float ph = __fmul_rn(expf(l.w), 32.0f);
    float hx = __fmul_rn(pw, 0.5f);
    float hy = __fmul_rn(ph, 0.5f);
    float x1 = __fsub_rn(px, hx), y1 = __fsub_rn(py, hy);
    float x2 = __fadd_rn(px, hx), y2 = __fadd_rn(py, hy);
    float4 b; b.x = x1; b.y = y1; b.z = x2; b.w = y2;
    boxes[i] = b;
    area[i] = __fmul_rn(__fsub_rn(x2, x1), __fsub_rn(y2, y1));

    const float4* cr = (const float4*)(cls + (size_t)i * NCLS);
    float mx = -INFINITY;
#pragma unroll
    for (int k = 0; k < 16; ++k) {
        float4 v = cr[k];
        mx = fmaxf(mx, fmaxf(fmaxf(v.x, v.y), fmaxf(v.z, v.w)));
    }
    float s;
    if (mx >= 0.0f) {
        float e = expf(-mx);
        s = __fdiv_rn(1.0f, __fadd_rn(1.0f, e));
    } else {
        float e = expf(mx);
        s = __fdiv_rn(e, __fadd_rn(1.0f, e));
    }
    score[i] = s;
    float se = (s > 0.5f) ? s : -INFINITY;   // score_eff
    u32 u = __float_as_uint(se);
    u = (u & 0x80000000u) ? ~u : (u | 0x80000000u);   // ascending-ordered uint; valid >= 0x80000000
    key[i] = u;
}

// ---------------- pairs: per-box EARLIER-neighbor (word, mask) sparse lists ----------------
// grid (48, 192): block = i-rows rg*64..+63 vs j-words 4wg..4wg+3.
// thread: wv = tid>>6 (word within group), row = tid&63.
__global__ void pairs_kernel(const float4* __restrict__ boxes, const float* __restrict__ area,
                             const u32* __restrict__ key, u64* __restrict__ rec8,
                             u8* __restrict__ ovw, u64* __restrict__ ovm) {
    int wg = blockIdx.x, rg = blockIdx.y;
    __shared__ float4 qbox[256]; __shared__ float qarea[256]; __shared__ u32 qkey[256];
    __shared__ float4 rbox[64];  __shared__ float rarea[64];  __shared__ u32 rkey[64];
    int tid = threadIdx.x;
    int qg = (wg << 8) + tid;
    float4 qb = boxes[qg];
    qbox[tid] = qb; qarea[tid] = area[qg]; qkey[tid] = key[qg];
    if (tid < 64) { int ig = (rg << 6) + tid; rbox[tid] = boxes[ig]; rarea[tid] = area[ig]; rkey[tid] = key[ig]; }
    // word bbox via wave butterfly over this wave's 64 q-boxes
    float qx1 = qb.x, qy1 = qb.y, qx2 = qb.z, qy2 = qb.w;
#pragma unroll
    for (int off = 1; off < 64; off <<= 1) {
        qx1 = fminf(qx1, __shfl_xor(qx1, off));
        qy1 = fminf(qy1, __shfl_xor(qy1, off));
        qx2 = fmaxf(qx2, __shfl_xor(qx2, off));
        qy2 = fmaxf(qy2, __shfl_xor(qy2, off));
    }
    __syncthreads();
    int row = tid & 63, wv = tid >> 6;
    int i = (rg << 6) + row;
    int W = (wg << 2) + wv;
    float4 bi = rbox[row];
    float ai = rarea[row];
    u32 ki = rkey[row];
    if (ki < 0x80000000u) return;   // invalid box: never kept, never examined
    // conservative overlap early-out vs word bbox (touching edges -> inter=0 -> iou=0, skip safe)
    if (bi.z <= qx1 || qx2 <= bi.x || bi.w <= qy1 || qy2 <= bi.y) return;
    u64 mask = 0;
    int qb0 = wv << 6;
#pragma unroll 8
    for (int j = 0; j < 64; ++j) {
        float4 bj = qbox[qb0 + j];
        float aj = qarea[qb0 + j];
        u32 kj = qkey[qb0 + j];
        bool e = (kj > ki) || ((kj == ki) && (((W << 6) + j) < i));   // j strictly earlier than i
        bool pred = e && iou_gt(bi, ai, bj, aj);
        mask |= ((u64)pred) << j;
    }
    if (mask) {
        u32 slot = atomicAdd((u32*)&rec8[(size_t)i * 8], 1u);
        if (slot < 6) {
            ((u8*)&rec8[(size_t)i * 8 + 1])[slot] = (u8)W;
            rec8[(size_t)i * 8 + 2 + slot] = mask;
        } else {
            u32 o = slot - 6;
            ovw[(size_t)i * CAPO + o] = (u8)W;
            ovm[(size_t)i * CAPO + o] = mask;
        }
    }
}

// ---------------- solve: synchronous fixpoint of keep[q] = valid[q] & all earlier nbrs not kept ----
// ONE block, 1024 threads, 12 boxes/thread. Read-phase / write-phase split by barriers.
__global__ void __launch_bounds__(1024)
solve_kernel(const u64* __restrict__ rec8, const u8* __restrict__ ovw,
             const u64* __restrict__ ovm, const float4* __restrict__ boxes,
             const float* __restrict__ score, float* __restrict__ out) {
    __shared__ u64 kept[TOTW];
    __shared__ u64 dec[TOTW];
    __shared__ int changed;
    int tid = threadIdx.x;
    for (int k = tid; k < TOTW; k += 1024) { kept[k] = 0ull; dec[k] = 0ull; }
    __syncthreads();

    u32 undec = 0;
#pragma unroll
    for (int b = 0; b < 12; ++b) {
        int i = tid + (b << 10);
        if (score[i] > 0.5f) undec |= (1u << b);
        else atomicOr(&dec[i >> 6], 1ull << (i & 63));   // invalid: decided, not kept
    }
    __syncthreads();

    for (int round = 0; round < 12300; ++round) {
        if (tid == 0) changed = 0;
        __syncthreads();                       // A: reset visible, prior writes frozen
        u32 dkeep = 0, dkill = 0;
        u32 u = undec;
        while (u) {
            int b = __ffs(u) - 1; u &= u - 1;
            int i = tid + (b << 10);
            const ulonglong4* rp = (const ulonglong4*)&rec8[(size_t)i * 8];
            ulonglong4 RA = rp[0];
            u32 wc = (u32)RA.x;
            u64 wb = RA.y;
            u32 w0 = (u32)(wb & 0xFF), w1 = (u32)((wb >> 8) & 0xFF);
            u64 anyk = 0, anyu = 0;
            if (wc > 0) { u64 m = RA.z; anyu |= m & ~dec[w0]; anyk |= m & kept[w0]; }
            if (wc > 1) { u64 m = RA.w; anyu |= m & ~dec[w1]; anyk |= m & kept[w1]; }
            if (wc > 2) {
                ulonglong4 RB = rp[1];
                u32 w2 = (u32)((wb >> 16) & 0xFF), w3 = (u32)((wb >> 24) & 0xFF);
                u32 w4 = (u32)((wb >> 32) & 0xFF), w5 = (u32)((wb >> 40) & 0xFF);
                { u64 m = RB.x; anyu |= m & ~dec[w2]; anyk |= m & kept[w2]; }
                if (wc > 3) { u64 m = RB.y; anyu |= m & ~dec[w3]; anyk |= m & kept[w3]; }
                if (wc > 4) { u64 m = RB.z; anyu |= m & ~dec[w4]; anyk |= m & kept[w4]; }
                if (wc > 5) { u64 m = RB.w; anyu |= m & ~dec[w5]; anyk |= m & kept[w5]; }
            }
            if (wc > 6) {
                u32 we = (wc <= 192u) ? wc : 192u;
                for (u32 k = 6; k < we; ++k) {
                    u32 Wo = ovw[(size_t)i * CAPO + (k - 6)];
                    u64 m = ovm[(size_t)i * CAPO + (k - 6)];
                    anyu |= m & ~dec[Wo]; anyk |= m & kept[Wo];
                }
            }
            if (anyk) dkill |= (1u << b);
            else if (!anyu) dkeep |= (1u << b);
        }
        __syncthreads();                       // B: all reads done before any write
        u32 dmask = dkeep | dkill;
        if (dmask) {
            changed = 1;
            u32 m2 = dmask;
            while (m2) {
                int b = __ffs(m2) - 1; m2 &= m2 - 1;
                int i = tid + (b << 10);
                if (dkeep & (1u << b)) atomicOr(&kept[i >> 6], 1ull << (i & 63));
                atomicOr(&dec[i >> 6], 1ull << (i & 63));
            }
            undec &= ~dmask;
        }
        __syncthreads();                       // C: writes visible
        int ch = changed;
        __syncthreads();                       // D: all read ch before next reset
        if (ch == 0) break;
    }

    // ---- output (kept is in original index space) ----
#pragma unroll
    for (int b = 0; b < 12; ++b) {
        int i = tid + (b << 10);
        float m = ((kept[i >> 6] >> (i & 63)) & 1ull) ? 1.0f : 0.0f;
        float4 bx = boxes[i];
        float s = score[i];
        out[(size_t)i * 5 + 0] = __fmul_rn(bx.x, m);
        out[(size_t)i * 5 + 1] = __fmul_rn(bx.y, m);
        out[(size_t)i * 5 + 2] = __fmul_rn(bx.z, m);
        out[(size_t)i * 5 + 3] = __fmul_rn(bx.w, m);
        out[(size_t)i * 5 + 4] = __fmul_rn(s, m);
    }
}

extern "C" void kernel_launch(void* const* d_in, const int* in_sizes, int n_in,
                              void* d_out, int out_size, void* d_ws, size_t ws_size,
                              hipStream_t stream) {
    const float4* loc = (const float4*)d_in[0];
    const float* cls = (const float*)d_in[1];
    char* ws = (char*)d_ws;

    float4* boxes = (float4*)(ws + 0);         // 196608
    float*  score = (float*) (ws + 196608);    // 49152
    u32*    key   = (u32*)   (ws + 245760);    // 49152
    float*  area  = (float*) (ws + 294912);    // 49152
    u64*    rec8  = (u64*)   (ws + 344064);    // 12288*64 = 786432 (64B-aligned)
    u8*     ovw   = (u8*)    (ws + 1130496);   // 12288*192 = 2359296
    u64*    ovm   = (u64*)   (ws + 3489792);   // 12288*192*8 = 18874368 (end ~22.4 MB)
    float*  out   = (float*)d_out;

    decode_kernel<<<48, 256, 0, stream>>>(loc, cls, boxes, score, key, area, rec8);
    pairs_kernel<<<dim3(48, 192), 256, 0, stream>>>(boxes, area, key, rec8, ovw, ovm);
    solve_kernel<<<1, 1024, 0, stream>>>(rec8, ovw, ovm, boxes, score, out);
}